// Round 1
// baseline (49.035 us; speedup 1.0000x reference)
//
#include <hip/hip_runtime.h>
#include <math.h>

// FRN projection head, MI355X.
// Math: hat = (StS+lam I)^-1 StS = I - lam*Minv ; B = rho*hat - I (symmetric)
//       G = B^2 ; neg_l2[img,n] = -(1/100) <G_n, C_img>,  C_img = A A^T (Gram)
// Minv via Gershgorin-bounded Chebyshev-1 init + 3 Newton-Schulz iterations,
// all 64x64 matmuls done with mfma_f32_16x16x32_bf16 (f32 accumulate).

typedef __attribute__((ext_vector_type(8))) short short8;   // 8 x bf16 bits
typedef __attribute__((ext_vector_type(4))) float f32x4;

#define NSUP 150
#define NQ 450
#define PIX 100
#define IMG_STRIDE 6400   // 64*100 floats per image

__device__ __forceinline__ short bf16r(float x) {          // f32 -> bf16 (RNE)
  unsigned u = __builtin_bit_cast(unsigned, x);
  u += 0x7FFFu + ((u >> 16) & 1u);
  return (short)(u >> 16);
}
__device__ __forceinline__ float b2f(short v) {
  return __builtin_bit_cast(float, ((unsigned)(unsigned short)v) << 16);
}

// Accumulate acc += A*A^T for one image (A = 64x100 f32, k padded to 128 w/ zeros).
// Tile (R,C) in standard C/D layout: row=R*16+(lane>>4)*4+q, col=C*16+(lane&15).
__device__ __forceinline__ void gram_accum(const float* __restrict__ f,
                                           f32x4 acc[4][4], int r, int g) {
  #pragma unroll
  for (int ks = 0; ks < 4; ++ks) {
    short8 frag[4];
    const int kb = ks * 32 + g * 8;
    #pragma unroll
    for (int R = 0; R < 4; ++R) {
      short8 q;
      const float* p = f + (R * 16 + r) * PIX + kb;
      if (ks < 3) {
        float4 lo = *(const float4*)p;
        float4 hi = *(const float4*)(p + 4);
        q[0] = bf16r(lo.x); q[1] = bf16r(lo.y); q[2] = bf16r(lo.z); q[3] = bf16r(lo.w);
        q[4] = bf16r(hi.x); q[5] = bf16r(hi.y); q[6] = bf16r(hi.z); q[7] = bf16r(hi.w);
      } else {
        if (g == 0) {                      // k = 96..99 valid, rest zero-pad
          float4 lo = *(const float4*)p;
          q[0] = bf16r(lo.x); q[1] = bf16r(lo.y); q[2] = bf16r(lo.z); q[3] = bf16r(lo.w);
          q[4] = 0; q[5] = 0; q[6] = 0; q[7] = 0;
        } else {
          #pragma unroll
          for (int j = 0; j < 8; ++j) q[j] = 0;
        }
      }
      frag[R] = q;
    }
    #pragma unroll
    for (int R = 0; R < 4; ++R)
      #pragma unroll
      for (int C = 0; C < 4; ++C)
        acc[R][C] = __builtin_amdgcn_mfma_f32_16x16x32_bf16(frag[R], frag[C],
                                                            acc[R][C], 0, 0, 0);
  }
}

// D = A*B for 64x64 bf16 matrices in LDS (row-major, stride 72 elems).
// B must be SYMMETRIC (B-fragment gathered as rows of B).
__device__ __forceinline__ void mm64(const short* A, const short* B,
                                     f32x4 acc[4][4], int r, int g) {
  #pragma unroll
  for (int ks = 0; ks < 2; ++ks) {
    short8 af[4], bfr[4];
    #pragma unroll
    for (int R = 0; R < 4; ++R) {
      af[R]  = *(const short8*)(A + (R * 16 + r) * 72 + ks * 32 + g * 8);
      bfr[R] = *(const short8*)(B + (R * 16 + r) * 72 + ks * 32 + g * 8);
    }
    #pragma unroll
    for (int R = 0; R < 4; ++R)
      #pragma unroll
      for (int C = 0; C < 4; ++C)
        acc[R][C] = __builtin_amdgcn_mfma_f32_16x16x32_bf16(af[R], bfr[C],
                                                            acc[R][C], 0, 0, 0);
  }
}

#define ZERO_ACC(t)                                   \
  _Pragma("unroll") for (int R = 0; R < 4; ++R)       \
  _Pragma("unroll") for (int C = 0; C < 4; ++C)       \
  _Pragma("unroll") for (int q = 0; q < 4; ++q) t[R][C][q] = 0.f;

__global__ __launch_bounds__(256) void k_solve(const float* __restrict__ feat,
                                               const float* __restrict__ rvec,
                                               float* __restrict__ Gneg) {
  __shared__ __align__(16) float Ms[64 * 65];
  __shared__ __align__(16) short Mb[64 * 72];
  __shared__ __align__(16) short Xb[64 * 72];
  __shared__ __align__(16) short Tb[64 * 72];
  __shared__ float sS, sTheta;

  const int n = blockIdx.x;
  const int tid = threadIdx.x;
  const int wave = tid >> 6, lane = tid & 63;
  const int r = lane & 15, g = lane >> 4;

  const float lam = 46.875f * expf(rvec[0]);   // reg = 3000/64
  const float rho = expf(rvec[1]);

  // phase 1: per-wave partial Gram over this class's 30 support images
  f32x4 acc[4][4];
  ZERO_ACC(acc)
  const int start = wave * 8;
  const int cnt = (30 - start < 8) ? (30 - start) : 8;   // 8,8,8,6
  for (int im = 0; im < cnt; ++im) {
    const float* f = feat + (size_t)(n * 30 + start + im) * IMG_STRIDE;
    gram_accum(f, acc, r, g);
  }

  // phase 2: sequential (deterministic) reduction of 4 wave-partials into Ms
  for (int w = 0; w < 4; ++w) {
    if (wave == w) {
      #pragma unroll
      for (int R = 0; R < 4; ++R)
        #pragma unroll
        for (int C = 0; C < 4; ++C)
          #pragma unroll
          for (int q = 0; q < 4; ++q) {
            const int row = R * 16 + g * 4 + q, col = C * 16 + r;
            const float v = acc[R][C][q] * (1.f / 64.f);   // inv_sqrt_d^2
            if (w == 0) Ms[row * 65 + col] = v;
            else        Ms[row * 65 + col] += v;
          }
    }
    __syncthreads();
  }
  if (tid < 64) Ms[tid * 65 + tid] += lam;
  __syncthreads();

  // phase 3: Gershgorin bounds -> Chebyshev degree-1 init params
  if (tid < 64) {
    const float diag = Ms[tid * 65 + tid];
    float rad = 0.f;
    for (int j = 0; j < 64; ++j) rad += fabsf(Ms[tid * 65 + j]);
    rad -= fabsf(diag);
    float lo = diag - rad, hi = diag + rad;
    for (int off = 32; off; off >>= 1) {
      lo = fminf(lo, __shfl_down(lo, off));
      hi = fmaxf(hi, __shfl_down(hi, off));
    }
    if (tid == 0) {
      const float a = fmaxf(lo, lam);   // spectrum >= lam (StS is PSD)
      const float b = hi;
      const float s = a + b, d = b - a;
      sS = s;
      sTheta = 8.f / (2.f * s * s - d * d);   // X0 = theta*(s*I - M)
    }
  }
  __syncthreads();
  const float s0 = sS, theta = sTheta;

  // phase 4: Mb = bf16(M); Xb = bf16(X0)
  for (int e = tid; e < 4096; e += 256) {
    const int i = e >> 6, j = e & 63;
    const float m = Ms[i * 65 + j];
    Mb[i * 72 + j] = bf16r(m);
    Xb[i * 72 + j] = bf16r(theta * (((i == j) ? s0 : 0.f) - m));
  }
  __syncthreads();

  // phase 5: 3 Newton-Schulz iterations, wave 0 only (X' = 2X - (X*M)*X)
  for (int it = 0; it < 3; ++it) {
    if (tid < 64) {
      f32x4 t[4][4];
      ZERO_ACC(t)
      mm64(Xb, Mb, t, r, g);            // T = X*M   (B-operand M symmetric)
      #pragma unroll
      for (int R = 0; R < 4; ++R)
        #pragma unroll
        for (int C = 0; C < 4; ++C)
          #pragma unroll
          for (int q = 0; q < 4; ++q) {
            const int row = R * 16 + g * 4 + q, col = C * 16 + r;
            Tb[row * 72 + col] = bf16r(t[R][C][q]);
          }
    }
    __syncthreads();
    if (tid < 64) {
      f32x4 t[4][4];
      ZERO_ACC(t)
      mm64(Tb, Xb, t, r, g);            // T*X   (B-operand X symmetric)
      #pragma unroll
      for (int R = 0; R < 4; ++R)
        #pragma unroll
        for (int C = 0; C < 4; ++C)
          #pragma unroll
          for (int q = 0; q < 4; ++q) {
            const int row = R * 16 + g * 4 + q, col = C * 16 + r;
            const int idx = row * 72 + col;
            const float xo = b2f(Xb[idx]);
            Xb[idx] = bf16r(2.f * xo - t[R][C][q]);
          }
    }
    __syncthreads();
  }

  // phase 6: B = (rho-1)*I - rho*lam*X  (into Tb; symmetric)
  for (int e = tid; e < 4096; e += 256) {
    const int i = e >> 6, j = e & 63;
    const float x = b2f(Xb[i * 72 + j]);
    Tb[i * 72 + j] = bf16r(((i == j) ? (rho - 1.f) : 0.f) - rho * lam * x);
  }
  __syncthreads();

  // phase 7: G = B*B ; store -G/100 (folds the -1/(h*w) of neg_l2_dist)
  if (tid < 64) {
    f32x4 t[4][4];
    ZERO_ACC(t)
    mm64(Tb, Tb, t, r, g);
    #pragma unroll
    for (int R = 0; R < 4; ++R)
      #pragma unroll
      for (int C = 0; C < 4; ++C)
        #pragma unroll
        for (int q = 0; q < 4; ++q) {
          const int row = R * 16 + g * 4 + q, col = C * 16 + r;
          Gneg[n * 4096 + row * 64 + col] = t[R][C][q] * (-0.01f);
        }
  }
}

__global__ __launch_bounds__(256) void k_dist(const float* __restrict__ feat,
                                              const float* __restrict__ Gneg,
                                              const float* __restrict__ scale,
                                              const int* __restrict__ label,
                                              float* __restrict__ out,
                                              float* __restrict__ lossbuf) {
  const int wave = threadIdx.x >> 6, lane = threadIdx.x & 63;
  const int img = blockIdx.x * 4 + wave;
  if (img >= NQ) return;                 // no barriers in this kernel
  const int r = lane & 15, g = lane >> 4;

  f32x4 acc[4][4];
  ZERO_ACC(acc)
  const float* f = feat + (size_t)(NSUP + img) * IMG_STRIDE;
  gram_accum(f, acc, r, g);              // C_img stays in registers

  float nl[5] = {0.f, 0.f, 0.f, 0.f, 0.f};
  #pragma unroll
  for (int R = 0; R < 4; ++R)
    #pragma unroll
    for (int C = 0; C < 4; ++C)
      #pragma unroll
      for (int q = 0; q < 4; ++q) {
        const int row = R * 16 + g * 4 + q, col = C * 16 + r;
        const float cv = acc[R][C][q] * (1.f / 64.f);
        const int idx = row * 64 + col;
        #pragma unroll
        for (int nn = 0; nn < 5; ++nn) nl[nn] += Gneg[nn * 4096 + idx] * cv;
      }

  #pragma unroll
  for (int nn = 0; nn < 5; ++nn)
    for (int off = 32; off; off >>= 1) nl[nn] += __shfl_down(nl[nn], off);

  if (lane == 0) {                       // nl[] = neg_l2_dist[img][0..4]
    float mx = nl[0];
    #pragma unroll
    for (int nn = 1; nn < 5; ++nn) mx = fmaxf(mx, nl[nn]);
    float ex[5], se = 0.f;
    #pragma unroll
    for (int nn = 0; nn < 5; ++nn) { ex[nn] = expf(nl[nn] - mx); se += ex[nn]; }
    const float inv = 1.f / se;
    #pragma unroll
    for (int nn = 0; nn < 5; ++nn) out[img * 5 + nn] = ex[nn] * inv;

    const float sc = scale[0];
    float mx2 = nl[0] * sc;
    #pragma unroll
    for (int nn = 1; nn < 5; ++nn) mx2 = fmaxf(mx2, nl[nn] * sc);
    float se2 = 0.f;
    #pragma unroll
    for (int nn = 0; nn < 5; ++nn) se2 += expf(nl[nn] * sc - mx2);
    const float lse = mx2 + logf(se2);
    lossbuf[img] = lse - nl[label[img]] * sc;   // -log p[label]
  }
}

__global__ __launch_bounds__(256) void k_loss(const float* __restrict__ lossbuf,
                                              float* __restrict__ out) {
  const int tid = threadIdx.x;
  float s = 0.f;
  for (int i = tid; i < NQ; i += 256) s += lossbuf[i];
  for (int off = 32; off; off >>= 1) s += __shfl_down(s, off);
  __shared__ float part[4];
  if ((tid & 63) == 0) part[tid >> 6] = s;
  __syncthreads();
  if (tid == 0) out[2250] = (part[0] + part[1] + part[2] + part[3]) / 450.f;
}

extern "C" void kernel_launch(void* const* d_in, const int* in_sizes, int n_in,
                              void* d_out, int out_size, void* d_ws, size_t ws_size,
                              hipStream_t stream) {
  const float* feat  = (const float*)d_in[0];
  const int*   label = (const int*)d_in[1];
  const float* scale = (const float*)d_in[2];
  const float* rvec  = (const float*)d_in[3];
  float* out = (float*)d_out;

  float* Gneg    = (float*)d_ws;          // 5*4096 f32  (-B^2/100 per class)
  float* lossbuf = Gneg + 5 * 4096;       // 450 f32     (~84 KB total ws use)

  k_solve<<<dim3(5),   dim3(256), 0, stream>>>(feat, rvec, Gneg);
  k_dist <<<dim3(113), dim3(256), 0, stream>>>(feat, Gneg, scale, label, out, lossbuf);
  k_loss <<<dim3(1),   dim3(256), 0, stream>>>(lossbuf, out);
}

// Round 2
// 30.784 us; speedup vs baseline: 1.5929x; 1.5929x over previous
//
#include <hip/hip_runtime.h>
#include <math.h>

// FRN projection head, MI355X.
// Math: hat = (StS+lam I)^-1 StS = I - lam*Minv ; B = rho*hat - I (symmetric)
//       G = B^2 ; neg_l2[img,n] = -(1/100) <G_n, C_img>,  C_img = A A^T (Gram)
// Minv via Gershgorin-bounded Chebyshev-1 init + 3 Newton-Schulz iterations,
// all 64x64 matmuls done with mfma_f32_16x16x32_bf16 (f32 accumulate).
//
// R1 restructure (latency-bound, occupancy 0.2%):
//  - k_gram: support Grams on 30 blocks (was serial 8 img/wave inside k_solve)
//  - k_solve: NS iterations quadrant-split across 4 waves (was 1 wave)

typedef __attribute__((ext_vector_type(8))) short short8;   // 8 x bf16 bits
typedef __attribute__((ext_vector_type(4))) float f32x4;

#define NSUP 150
#define NQ 450
#define PIX 100
#define IMG_STRIDE 6400   // 64*100 floats per image

__device__ __forceinline__ short bf16r(float x) {          // f32 -> bf16 (RNE)
  unsigned u = __builtin_bit_cast(unsigned, x);
  u += 0x7FFFu + ((u >> 16) & 1u);
  return (short)(u >> 16);
}
__device__ __forceinline__ float b2f(short v) {
  return __builtin_bit_cast(float, ((unsigned)(unsigned short)v) << 16);
}

// Accumulate acc += A*A^T for one image (A = 64x100 f32, k padded to 128 w/ zeros).
// Tile (R,C) in standard C/D layout: row=R*16+(lane>>4)*4+q, col=C*16+(lane&15).
__device__ __forceinline__ void gram_accum(const float* __restrict__ f,
                                           f32x4 acc[4][4], int r, int g) {
  #pragma unroll
  for (int ks = 0; ks < 4; ++ks) {
    short8 frag[4];
    const int kb = ks * 32 + g * 8;
    #pragma unroll
    for (int R = 0; R < 4; ++R) {
      short8 q;
      const float* p = f + (R * 16 + r) * PIX + kb;
      if (ks < 3) {
        float4 lo = *(const float4*)p;
        float4 hi = *(const float4*)(p + 4);
        q[0] = bf16r(lo.x); q[1] = bf16r(lo.y); q[2] = bf16r(lo.z); q[3] = bf16r(lo.w);
        q[4] = bf16r(hi.x); q[5] = bf16r(hi.y); q[6] = bf16r(hi.z); q[7] = bf16r(hi.w);
      } else {
        if (g == 0) {                      // k = 96..99 valid, rest zero-pad
          float4 lo = *(const float4*)p;
          q[0] = bf16r(lo.x); q[1] = bf16r(lo.y); q[2] = bf16r(lo.z); q[3] = bf16r(lo.w);
          q[4] = 0; q[5] = 0; q[6] = 0; q[7] = 0;
        } else {
          #pragma unroll
          for (int j = 0; j < 8; ++j) q[j] = 0;
        }
      }
      frag[R] = q;
    }
    #pragma unroll
    for (int R = 0; R < 4; ++R)
      #pragma unroll
      for (int C = 0; C < 4; ++C)
        acc[R][C] = __builtin_amdgcn_mfma_f32_16x16x32_bf16(frag[R], frag[C],
                                                            acc[R][C], 0, 0, 0);
  }
}

// Quadrant (wr,wc) of D = A*B for 64x64 bf16 LDS matrices (stride 72).
// B must be SYMMETRIC (B-fragment gathered as rows of B).
__device__ __forceinline__ void mm64q(const short* A, const short* B,
                                      f32x4 t[2][2], int r, int g, int wr, int wc) {
  #pragma unroll
  for (int ks = 0; ks < 2; ++ks) {
    short8 af[2], bfr[2];
    #pragma unroll
    for (int i = 0; i < 2; ++i) {
      af[i]  = *(const short8*)(A + (wr * 32 + i * 16 + r) * 72 + ks * 32 + g * 8);
      bfr[i] = *(const short8*)(B + (wc * 32 + i * 16 + r) * 72 + ks * 32 + g * 8);
    }
    #pragma unroll
    for (int i = 0; i < 2; ++i)
      #pragma unroll
      for (int j = 0; j < 2; ++j)
        t[i][j] = __builtin_amdgcn_mfma_f32_16x16x32_bf16(af[i], bfr[j],
                                                          t[i][j], 0, 0, 0);
  }
}

#define ZERO_ACC4(t)                                  \
  _Pragma("unroll") for (int R = 0; R < 4; ++R)       \
  _Pragma("unroll") for (int C = 0; C < 4; ++C)       \
  _Pragma("unroll") for (int q = 0; q < 4; ++q) t[R][C][q] = 0.f;

#define ZERO_ACC2(t)                                  \
  _Pragma("unroll") for (int R = 0; R < 2; ++R)       \
  _Pragma("unroll") for (int C = 0; C < 2; ++C)       \
  _Pragma("unroll") for (int q = 0; q < 4; ++q) t[R][C][q] = 0.f;

// 30 blocks: 5 classes x 6 blocks, 5 support images each. Waves split k-chunks.
__global__ __launch_bounds__(256) void k_gram(const float* __restrict__ feat,
                                              float* __restrict__ partial) {
  __shared__ __align__(16) float buf[4][4096];
  const int b = blockIdx.x;
  const int cls = b / 6, jb = b % 6;
  const int tid = threadIdx.x;
  const int wave = tid >> 6, lane = tid & 63;
  const int r = lane & 15, g = lane >> 4;
  const int ks = wave;                    // this wave's k-chunk (0..3)
  const int kb = ks * 32 + g * 8;

  f32x4 acc[4][4];
  ZERO_ACC4(acc)
  for (int im = 0; im < 5; ++im) {
    const float* f = feat + (size_t)(cls * 30 + jb * 5 + im) * IMG_STRIDE;
    short8 frag[4];
    #pragma unroll
    for (int R = 0; R < 4; ++R) {
      short8 q;
      const float* p = f + (R * 16 + r) * PIX + kb;
      if (ks < 3) {
        float4 lo = *(const float4*)p;
        float4 hi = *(const float4*)(p + 4);
        q[0] = bf16r(lo.x); q[1] = bf16r(lo.y); q[2] = bf16r(lo.z); q[3] = bf16r(lo.w);
        q[4] = bf16r(hi.x); q[5] = bf16r(hi.y); q[6] = bf16r(hi.z); q[7] = bf16r(hi.w);
      } else if (g == 0) {
        float4 lo = *(const float4*)p;
        q[0] = bf16r(lo.x); q[1] = bf16r(lo.y); q[2] = bf16r(lo.z); q[3] = bf16r(lo.w);
        q[4] = 0; q[5] = 0; q[6] = 0; q[7] = 0;
      } else {
        #pragma unroll
        for (int j = 0; j < 8; ++j) q[j] = 0;
      }
      frag[R] = q;
    }
    #pragma unroll
    for (int R = 0; R < 4; ++R)
      #pragma unroll
      for (int C = 0; C < 4; ++C)
        acc[R][C] = __builtin_amdgcn_mfma_f32_16x16x32_bf16(frag[R], frag[C],
                                                            acc[R][C], 0, 0, 0);
  }

  #pragma unroll
  for (int R = 0; R < 4; ++R)
    #pragma unroll
    for (int C = 0; C < 4; ++C)
      #pragma unroll
      for (int q = 0; q < 4; ++q) {
        const int row = R * 16 + g * 4 + q, col = C * 16 + r;
        buf[wave][row * 64 + col] = acc[R][C][q];
      }
  __syncthreads();

  float* outp = partial + (size_t)b * 4096;
  for (int c = tid; c < 1024; c += 256) {
    f32x4 s0 = *(const f32x4*)&buf[0][4 * c];
    f32x4 s1 = *(const f32x4*)&buf[1][4 * c];
    f32x4 s2 = *(const f32x4*)&buf[2][4 * c];
    f32x4 s3 = *(const f32x4*)&buf[3][4 * c];
    f32x4 s = s0 + s1 + s2 + s3;
    *(float4*)(outp + 4 * c) = *(float4*)&s;
  }
}

__global__ __launch_bounds__(256) void k_solve(const float* __restrict__ partial,
                                               const float* __restrict__ rvec,
                                               float* __restrict__ Gneg) {
  __shared__ __align__(16) float Ms[64 * 65];
  __shared__ __align__(16) short Mb[64 * 72];
  __shared__ __align__(16) short Tb[64 * 72];
  __shared__ __align__(16) short Xa[64 * 72];
  __shared__ __align__(16) short Xc[64 * 72];
  __shared__ float radp[4][64];
  __shared__ float sS, sTheta;

  const int n = blockIdx.x;
  const int tid = threadIdx.x;
  const int wave = tid >> 6, lane = tid & 63;
  const int r = lane & 15, g = lane >> 4;
  const int wr = wave >> 1, wc = wave & 1;

  const float lam = 46.875f * expf(rvec[0]);   // reg = 3000/64
  const float rho = expf(rvec[1]);

  // phase 1: M = (1/64) * sum of this class's 6 partial Grams (coalesced)
  {
    const float* base = partial + (size_t)n * 6 * 4096;
    for (int c = tid; c < 1024; c += 256) {
      float4 s = {0.f, 0.f, 0.f, 0.f};
      #pragma unroll
      for (int p = 0; p < 6; ++p) {
        float4 v = *(const float4*)(base + p * 4096 + 4 * c);
        s.x += v.x; s.y += v.y; s.z += v.z; s.w += v.w;
      }
      const int e = 4 * c, row = e >> 6, col = e & 63;
      Ms[row * 65 + col + 0] = s.x * (1.f / 64.f);
      Ms[row * 65 + col + 1] = s.y * (1.f / 64.f);
      Ms[row * 65 + col + 2] = s.z * (1.f / 64.f);
      Ms[row * 65 + col + 3] = s.w * (1.f / 64.f);
    }
  }
  __syncthreads();
  if (tid < 64) Ms[tid * 65 + tid] += lam;
  __syncthreads();

  // phase 3: Gershgorin bounds (4 threads per row) -> Chebyshev-1 init params
  {
    const int row = tid & 63, part = tid >> 6;
    float s = 0.f;
    #pragma unroll
    for (int k = 0; k < 16; ++k) s += fabsf(Ms[row * 65 + part * 16 + k]);
    radp[part][row] = s;
  }
  __syncthreads();
  if (tid < 64) {
    const float diag = Ms[tid * 65 + tid];
    const float rad = radp[0][tid] + radp[1][tid] + radp[2][tid] + radp[3][tid]
                      - fabsf(diag);
    float lo = diag - rad, hi = diag + rad;
    for (int off = 32; off; off >>= 1) {
      lo = fminf(lo, __shfl_down(lo, off));
      hi = fmaxf(hi, __shfl_down(hi, off));
    }
    if (tid == 0) {
      const float a = fmaxf(lo, lam);   // spectrum >= lam (StS is PSD)
      const float b = hi;
      const float s = a + b, d = b - a;
      sS = s;
      sTheta = 8.f / (2.f * s * s - d * d);   // X0 = theta*(s*I - M)
    }
  }
  __syncthreads();
  const float s0 = sS, theta = sTheta;

  // phase 4: Mb = bf16(M); Xa = bf16(X0)
  for (int e = tid; e < 4096; e += 256) {
    const int i = e >> 6, j = e & 63;
    const float m = Ms[i * 65 + j];
    Mb[i * 72 + j] = bf16r(m);
    Xa[i * 72 + j] = bf16r(theta * (((i == j) ? s0 : 0.f) - m));
  }
  __syncthreads();

  // phase 5: 3 Newton-Schulz iterations, quadrant-split across 4 waves.
  // X ping-pongs Xa<->Xc (other waves read X's full rows via symmetry).
  short* x  = Xa;
  short* xn = Xc;
  for (int it = 0; it < 3; ++it) {
    {
      f32x4 t[2][2];
      ZERO_ACC2(t)
      mm64q(x, Mb, t, r, g, wr, wc);          // T = X*M (M symmetric)
      #pragma unroll
      for (int i = 0; i < 2; ++i)
        #pragma unroll
        for (int j = 0; j < 2; ++j)
          #pragma unroll
          for (int q = 0; q < 4; ++q) {
            const int row = wr * 32 + i * 16 + g * 4 + q;
            const int col = wc * 32 + j * 16 + r;
            Tb[row * 72 + col] = bf16r(t[i][j][q]);
          }
    }
    __syncthreads();
    {
      f32x4 t[2][2];
      ZERO_ACC2(t)
      mm64q(Tb, x, t, r, g, wr, wc);          // T*X (X ~symmetric)
      #pragma unroll
      for (int i = 0; i < 2; ++i)
        #pragma unroll
        for (int j = 0; j < 2; ++j)
          #pragma unroll
          for (int q = 0; q < 4; ++q) {
            const int row = wr * 32 + i * 16 + g * 4 + q;
            const int col = wc * 32 + j * 16 + r;
            const int idx = row * 72 + col;
            xn[idx] = bf16r(2.f * b2f(x[idx]) - t[i][j][q]);
          }
    }
    __syncthreads();
    short* tmp = x; x = xn; xn = tmp;
  }

  // phase 6: B = (rho-1)*I - rho*lam*X  (into Tb; symmetric)
  for (int e = tid; e < 4096; e += 256) {
    const int i = e >> 6, j = e & 63;
    const float xv = b2f(x[i * 72 + j]);
    Tb[i * 72 + j] = bf16r(((i == j) ? (rho - 1.f) : 0.f) - rho * lam * xv);
  }
  __syncthreads();

  // phase 7: G = B*B ; store -G/100 (folds the -1/(h*w) of neg_l2_dist)
  {
    f32x4 t[2][2];
    ZERO_ACC2(t)
    mm64q(Tb, Tb, t, r, g, wr, wc);
    #pragma unroll
    for (int i = 0; i < 2; ++i)
      #pragma unroll
      for (int j = 0; j < 2; ++j)
        #pragma unroll
        for (int q = 0; q < 4; ++q) {
          const int row = wr * 32 + i * 16 + g * 4 + q;
          const int col = wc * 32 + j * 16 + r;
          Gneg[n * 4096 + row * 64 + col] = t[i][j][q] * (-0.01f);
        }
  }
}

__global__ __launch_bounds__(256) void k_dist(const float* __restrict__ feat,
                                              const float* __restrict__ Gneg,
                                              const float* __restrict__ scale,
                                              const int* __restrict__ label,
                                              float* __restrict__ out,
                                              float* __restrict__ lossbuf) {
  const int wave = threadIdx.x >> 6, lane = threadIdx.x & 63;
  const int img = blockIdx.x * 4 + wave;
  if (img >= NQ) return;                 // no barriers in this kernel
  const int r = lane & 15, g = lane >> 4;

  f32x4 acc[4][4];
  ZERO_ACC4(acc)
  const float* f = feat + (size_t)(NSUP + img) * IMG_STRIDE;
  gram_accum(f, acc, r, g);              // C_img stays in registers

  float nl[5] = {0.f, 0.f, 0.f, 0.f, 0.f};
  #pragma unroll
  for (int R = 0; R < 4; ++R)
    #pragma unroll
    for (int C = 0; C < 4; ++C)
      #pragma unroll
      for (int q = 0; q < 4; ++q) {
        const int row = R * 16 + g * 4 + q, col = C * 16 + r;
        const float cv = acc[R][C][q] * (1.f / 64.f);
        const int idx = row * 64 + col;
        #pragma unroll
        for (int nn = 0; nn < 5; ++nn) nl[nn] += Gneg[nn * 4096 + idx] * cv;
      }

  #pragma unroll
  for (int nn = 0; nn < 5; ++nn)
    for (int off = 32; off; off >>= 1) nl[nn] += __shfl_down(nl[nn], off);

  if (lane == 0) {                       // nl[] = neg_l2_dist[img][0..4]
    float mx = nl[0];
    #pragma unroll
    for (int nn = 1; nn < 5; ++nn) mx = fmaxf(mx, nl[nn]);
    float ex[5], se = 0.f;
    #pragma unroll
    for (int nn = 0; nn < 5; ++nn) { ex[nn] = expf(nl[nn] - mx); se += ex[nn]; }
    const float inv = 1.f / se;
    #pragma unroll
    for (int nn = 0; nn < 5; ++nn) out[img * 5 + nn] = ex[nn] * inv;

    const float sc = scale[0];
    float mx2 = nl[0] * sc;
    #pragma unroll
    for (int nn = 1; nn < 5; ++nn) mx2 = fmaxf(mx2, nl[nn] * sc);
    float se2 = 0.f;
    #pragma unroll
    for (int nn = 0; nn < 5; ++nn) se2 += expf(nl[nn] * sc - mx2);
    const float lse = mx2 + logf(se2);
    lossbuf[img] = lse - nl[label[img]] * sc;   // -log p[label]
  }
}

__global__ __launch_bounds__(256) void k_loss(const float* __restrict__ lossbuf,
                                              float* __restrict__ out) {
  const int tid = threadIdx.x;
  float s = 0.f;
  for (int i = tid; i < NQ; i += 256) s += lossbuf[i];
  for (int off = 32; off; off >>= 1) s += __shfl_down(s, off);
  __shared__ float part[4];
  if ((tid & 63) == 0) part[tid >> 6] = s;
  __syncthreads();
  if (tid == 0) out[2250] = (part[0] + part[1] + part[2] + part[3]) / 450.f;
}

extern "C" void kernel_launch(void* const* d_in, const int* in_sizes, int n_in,
                              void* d_out, int out_size, void* d_ws, size_t ws_size,
                              hipStream_t stream) {
  const float* feat  = (const float*)d_in[0];
  const int*   label = (const int*)d_in[1];
  const float* scale = (const float*)d_in[2];
  const float* rvec  = (const float*)d_in[3];
  float* out = (float*)d_out;

  float* partial = (float*)d_ws;            // 30*4096 f32 per-block class partials
  float* Gneg    = partial + 30 * 4096;     // 5*4096 f32  (-B^2/100 per class)
  float* lossbuf = Gneg + 5 * 4096;         // 450 f32   (~576 KB total ws use)

  k_gram <<<dim3(30),  dim3(256), 0, stream>>>(feat, partial);
  k_solve<<<dim3(5),   dim3(256), 0, stream>>>(partial, rvec, Gneg);
  k_dist <<<dim3(113), dim3(256), 0, stream>>>(feat, Gneg, scale, label, out, lossbuf);
  k_loss <<<dim3(1),   dim3(256), 0, stream>>>(lossbuf, out);
}

// Round 3
// 26.390 us; speedup vs baseline: 1.8581x; 1.1665x over previous
//
#include <hip/hip_runtime.h>
#include <math.h>

// FRN projection head, MI355X — single fused kernel.
// Math: hat = (StS+lam I)^-1 StS = I - lam*Minv ; B = rho*hat - I (symmetric)
//       G = B^2 ; neg_l2[img,n] = -(1/100) <G_n, C_img>,  C_img = A A^T (Gram)
// Minv via Gershgorin-bounded Chebyshev-1 init + 2 Newton-Schulz iterations.
// R2: fuse 4 kernels -> 1; inter-block deps via device-scope flags (guide G16).
//  - blocks 0..29 : support-Gram partials (5 imgs, 4-wave k-split) -> flag
//  - blocks 0..4  : + per-class solve (quadrant NS on 4 waves) -> G bf16 -> flag
//  - blocks 30..142: query Grams in regs (overlaps solve), wait, dot, softmax
//  - block 30     : gathers 113 per-block loss partials (fixed order)
// Grid 143 blocks x 64KB LDS -> 2 blocks/CU -> all co-resident: no deadlock.

typedef __attribute__((ext_vector_type(8))) short short8;   // 8 x bf16 bits
typedef __attribute__((ext_vector_type(4))) short short4v;  // 4 x bf16 bits
typedef __attribute__((ext_vector_type(4))) float f32x4;

#define NSUP 150
#define NQ 450
#define PIX 100
#define IMG_STRIDE 6400   // 64*100 floats per image
#define MAGIC 0x5F3D2B1Cu

static __device__ __forceinline__ short bf16r(float x) {   // f32 -> bf16 (RNE)
  unsigned u = __builtin_bit_cast(unsigned, x);
  u += 0x7FFFu + ((u >> 16) & 1u);
  return (short)(u >> 16);
}
static __device__ __forceinline__ float b2f(short v) {
  return __builtin_bit_cast(float, ((unsigned)(unsigned short)v) << 16);
}
static __device__ __forceinline__ void st_flag(unsigned* p, unsigned v) {
  __threadfence();
  __hip_atomic_store(p, v, __ATOMIC_RELEASE, __HIP_MEMORY_SCOPE_AGENT);
}
static __device__ __forceinline__ void spin_flag(unsigned* p) {
  int guard = 1 << 22;
  while (__hip_atomic_load(p, __ATOMIC_ACQUIRE, __HIP_MEMORY_SCOPE_AGENT) != MAGIC
         && --guard) __builtin_amdgcn_s_sleep(2);
}

// Accumulate acc += A*A^T for one image (A = 64x100 f32, k padded to 128).
// C/D layout: row = R*16 + (lane>>4)*4 + q, col = C*16 + (lane&15).
static __device__ __forceinline__ void gram_accum(const float* __restrict__ f,
                                                  f32x4 acc[4][4], int r, int g) {
  #pragma unroll
  for (int ks = 0; ks < 4; ++ks) {
    short8 frag[4];
    const int kb = ks * 32 + g * 8;
    #pragma unroll
    for (int R = 0; R < 4; ++R) {
      short8 q;
      const float* p = f + (R * 16 + r) * PIX + kb;
      if (ks < 3) {
        float4 lo = *(const float4*)p;
        float4 hi = *(const float4*)(p + 4);
        q[0] = bf16r(lo.x); q[1] = bf16r(lo.y); q[2] = bf16r(lo.z); q[3] = bf16r(lo.w);
        q[4] = bf16r(hi.x); q[5] = bf16r(hi.y); q[6] = bf16r(hi.z); q[7] = bf16r(hi.w);
      } else if (g == 0) {                 // k = 96..99 valid, rest zero-pad
        float4 lo = *(const float4*)p;
        q[0] = bf16r(lo.x); q[1] = bf16r(lo.y); q[2] = bf16r(lo.z); q[3] = bf16r(lo.w);
        q[4] = 0; q[5] = 0; q[6] = 0; q[7] = 0;
      } else {
        #pragma unroll
        for (int j = 0; j < 8; ++j) q[j] = 0;
      }
      frag[R] = q;
    }
    #pragma unroll
    for (int R = 0; R < 4; ++R)
      #pragma unroll
      for (int C = 0; C < 4; ++C)
        acc[R][C] = __builtin_amdgcn_mfma_f32_16x16x32_bf16(frag[R], frag[C],
                                                            acc[R][C], 0, 0, 0);
  }
}

// Quadrant (wr,wc) of D = A*B for 64x64 bf16 LDS matrices (stride 72).
// B must be SYMMETRIC (B-fragment gathered as rows of B).
static __device__ __forceinline__ void mm64q(const short* A, const short* B,
                                             f32x4 t[2][2], int r, int g,
                                             int wr, int wc) {
  #pragma unroll
  for (int ks = 0; ks < 2; ++ks) {
    short8 af[2], bfr[2];
    #pragma unroll
    for (int i = 0; i < 2; ++i) {
      af[i]  = *(const short8*)(A + (wr * 32 + i * 16 + r) * 72 + ks * 32 + g * 8);
      bfr[i] = *(const short8*)(B + (wc * 32 + i * 16 + r) * 72 + ks * 32 + g * 8);
    }
    #pragma unroll
    for (int i = 0; i < 2; ++i)
      #pragma unroll
      for (int j = 0; j < 2; ++j)
        t[i][j] = __builtin_amdgcn_mfma_f32_16x16x32_bf16(af[i], bfr[j],
                                                          t[i][j], 0, 0, 0);
  }
}

#define ZERO_ACC4(t)                                  \
  _Pragma("unroll") for (int R = 0; R < 4; ++R)       \
  _Pragma("unroll") for (int C = 0; C < 4; ++C)       \
  _Pragma("unroll") for (int q = 0; q < 4; ++q) t[R][C][q] = 0.f;

#define ZERO_ACC2(t)                                  \
  _Pragma("unroll") for (int R = 0; R < 2; ++R)       \
  _Pragma("unroll") for (int C = 0; C < 2; ++C)       \
  _Pragma("unroll") for (int q = 0; q < 4; ++q) t[R][C][q] = 0.f;

__global__ __launch_bounds__(256) void k_fused(
    const float* __restrict__ feat, const int* __restrict__ label,
    const float* __restrict__ scale, const float* __restrict__ rvec,
    float* __restrict__ out,
    float* __restrict__ partial,            // 30*4096 f32
    unsigned short* __restrict__ Gneg,      // 5*4096 bf16 (-B^2/100)
    float* __restrict__ blockloss,          // 113 f32
    unsigned* __restrict__ gflag,           // 30
    unsigned* __restrict__ sflag,           // 5
    unsigned* __restrict__ lflag) {         // 113
  __shared__ __align__(16) char smem[65536];
  const int b = blockIdx.x, tid = threadIdx.x;
  const int wave = tid >> 6, lane = tid & 63;
  const int r = lane & 15, g = lane >> 4;

  if (b < 30) {
    // ================= support-Gram partial (class b/6, group b%6) ==========
    float (*gbuf)[4096] = (float (*)[4096])smem;
    const int cls = b / 6, jb = b % 6;
    const int ks = wave, kb = ks * 32 + g * 8;
    f32x4 acc[4][4];
    ZERO_ACC4(acc)
    for (int im = 0; im < 5; ++im) {
      const float* f = feat + (size_t)(cls * 30 + jb * 5 + im) * IMG_STRIDE;
      short8 frag[4];
      #pragma unroll
      for (int R = 0; R < 4; ++R) {
        short8 q;
        const float* p = f + (R * 16 + r) * PIX + kb;
        if (ks < 3) {
          float4 lo = *(const float4*)p;
          float4 hi = *(const float4*)(p + 4);
          q[0] = bf16r(lo.x); q[1] = bf16r(lo.y); q[2] = bf16r(lo.z); q[3] = bf16r(lo.w);
          q[4] = bf16r(hi.x); q[5] = bf16r(hi.y); q[6] = bf16r(hi.z); q[7] = bf16r(hi.w);
        } else if (g == 0) {
          float4 lo = *(const float4*)p;
          q[0] = bf16r(lo.x); q[1] = bf16r(lo.y); q[2] = bf16r(lo.z); q[3] = bf16r(lo.w);
          q[4] = 0; q[5] = 0; q[6] = 0; q[7] = 0;
        } else {
          #pragma unroll
          for (int j = 0; j < 8; ++j) q[j] = 0;
        }
        frag[R] = q;
      }
      #pragma unroll
      for (int R = 0; R < 4; ++R)
        #pragma unroll
        for (int C = 0; C < 4; ++C)
          acc[R][C] = __builtin_amdgcn_mfma_f32_16x16x32_bf16(frag[R], frag[C],
                                                              acc[R][C], 0, 0, 0);
    }
    #pragma unroll
    for (int R = 0; R < 4; ++R)
      #pragma unroll
      for (int C = 0; C < 4; ++C)
        #pragma unroll
        for (int q = 0; q < 4; ++q) {
          const int row = R * 16 + g * 4 + q, col = C * 16 + r;
          gbuf[wave][row * 64 + col] = acc[R][C][q];
        }
    __syncthreads();
    float* outp = partial + (size_t)b * 4096;
    for (int c = tid; c < 1024; c += 256) {
      f32x4 s0 = *(const f32x4*)&gbuf[0][4 * c];
      f32x4 s1 = *(const f32x4*)&gbuf[1][4 * c];
      f32x4 s2 = *(const f32x4*)&gbuf[2][4 * c];
      f32x4 s3 = *(const f32x4*)&gbuf[3][4 * c];
      f32x4 s = s0 + s1 + s2 + s3;
      *(float4*)(outp + 4 * c) = *(float4*)&s;
    }
    __syncthreads();                         // gbuf dead; smem reused below
    if (tid == 0) st_flag(&gflag[b], MAGIC);
    if (b >= 5) return;

    // ======================= per-class solve (class n = b) ==================
    float* Ms   = (float*)(smem);            // 64*65 f32
    short* Mb   = (short*)(smem + 16640);    // 64*72 bf16
    short* Tb   = (short*)(smem + 25856);
    short* Xa   = (short*)(smem + 35072);
    short* Xc   = (short*)(smem + 44288);
    float* radp = (float*)(smem + 53504);    // [4][64]
    float* scal = (float*)(smem + 54528);    // sS, sTheta

    const int n = b;
    const int wr = wave >> 1, wc = wave & 1;
    const float lam = 46.875f * expf(rvec[0]);   // reg = 3000/64
    const float rho = expf(rvec[1]);

    if (tid == 0)
      for (int i = 0; i < 6; ++i) spin_flag(&gflag[6 * n + i]);
    __syncthreads();

    {  // M = (1/64) * sum of 6 partials (+ lam on diag)
      const float* base = partial + (size_t)n * 6 * 4096;
      for (int c = tid; c < 1024; c += 256) {
        float4 s = {0.f, 0.f, 0.f, 0.f};
        #pragma unroll
        for (int p = 0; p < 6; ++p) {
          float4 v = *(const float4*)(base + p * 4096 + 4 * c);
          s.x += v.x; s.y += v.y; s.z += v.z; s.w += v.w;
        }
        const int e = 4 * c, row = e >> 6, col = e & 63;
        Ms[row * 65 + col + 0] = s.x * (1.f / 64.f);
        Ms[row * 65 + col + 1] = s.y * (1.f / 64.f);
        Ms[row * 65 + col + 2] = s.z * (1.f / 64.f);
        Ms[row * 65 + col + 3] = s.w * (1.f / 64.f);
      }
    }
    __syncthreads();
    if (tid < 64) Ms[tid * 65 + tid] += lam;
    __syncthreads();

    {  // Gershgorin (4 threads/row) -> Chebyshev-1 init params
      const int row = tid & 63, part = tid >> 6;
      float s = 0.f;
      #pragma unroll
      for (int k = 0; k < 16; ++k) s += fabsf(Ms[row * 65 + part * 16 + k]);
      radp[part * 64 + row] = s;
    }
    __syncthreads();
    if (tid < 64) {
      const float diag = Ms[tid * 65 + tid];
      const float rad = radp[tid] + radp[64 + tid] + radp[128 + tid] +
                        radp[192 + tid] - fabsf(diag);
      float lo = diag - rad, hi = diag + rad;
      for (int off = 32; off; off >>= 1) {
        lo = fminf(lo, __shfl_down(lo, off));
        hi = fmaxf(hi, __shfl_down(hi, off));
      }
      if (tid == 0) {
        const float a = fmaxf(lo, lam);   // spectrum >= lam (StS is PSD)
        const float bb = hi;
        const float s = a + bb, d = bb - a;
        scal[0] = s;
        scal[1] = 8.f / (2.f * s * s - d * d);   // X0 = theta*(s*I - M)
      }
    }
    __syncthreads();
    const float s0 = scal[0], theta = scal[1];

    for (int e = tid; e < 4096; e += 256) {      // Mb, X0
      const int i = e >> 6, j = e & 63;
      const float m = Ms[i * 65 + j];
      Mb[i * 72 + j] = bf16r(m);
      Xa[i * 72 + j] = bf16r(theta * (((i == j) ? s0 : 0.f) - m));
    }
    __syncthreads();

    short* x = Xa;                               // 2 Newton-Schulz iterations
    short* xn = Xc;
    for (int it = 0; it < 2; ++it) {
      {
        f32x4 t[2][2];
        ZERO_ACC2(t)
        mm64q(x, Mb, t, r, g, wr, wc);           // T = X*M (M symmetric)
        #pragma unroll
        for (int i = 0; i < 2; ++i)
          #pragma unroll
          for (int j = 0; j < 2; ++j)
            #pragma unroll
            for (int q = 0; q < 4; ++q) {
              const int row = wr * 32 + i * 16 + g * 4 + q;
              const int col = wc * 32 + j * 16 + r;
              Tb[row * 72 + col] = bf16r(t[i][j][q]);
            }
      }
      __syncthreads();
      {
        f32x4 t[2][2];
        ZERO_ACC2(t)
        mm64q(Tb, x, t, r, g, wr, wc);           // T*X (X ~symmetric)
        #pragma unroll
        for (int i = 0; i < 2; ++i)
          #pragma unroll
          for (int j = 0; j < 2; ++j)
            #pragma unroll
            for (int q = 0; q < 4; ++q) {
              const int row = wr * 32 + i * 16 + g * 4 + q;
              const int col = wc * 32 + j * 16 + r;
              const int idx = row * 72 + col;
              xn[idx] = bf16r(2.f * b2f(x[idx]) - t[i][j][q]);
            }
      }
      __syncthreads();
      short* tmp = x; x = xn; xn = tmp;
    }

    for (int e = tid; e < 4096; e += 256) {      // B = (rho-1)I - rho*lam*X
      const int i = e >> 6, j = e & 63;
      const float xv = b2f(x[i * 72 + j]);
      Tb[i * 72 + j] = bf16r(((i == j) ? (rho - 1.f) : 0.f) - rho * lam * xv);
    }
    __syncthreads();

    {  // G = B*B ; store bf16(-G/100)
      f32x4 t[2][2];
      ZERO_ACC2(t)
      mm64q(Tb, Tb, t, r, g, wr, wc);
      #pragma unroll
      for (int i = 0; i < 2; ++i)
        #pragma unroll
        for (int j = 0; j < 2; ++j)
          #pragma unroll
          for (int q = 0; q < 4; ++q) {
            const int row = wr * 32 + i * 16 + g * 4 + q;
            const int col = wc * 32 + j * 16 + r;
            Gneg[n * 4096 + row * 64 + col] =
                (unsigned short)bf16r(t[i][j][q] * (-0.01f));
          }
    }
    __syncthreads();
    if (tid == 0) st_flag(&sflag[n], MAGIC);
    return;
  }

  // ======================= query dist + softmax + loss ======================
  const int img = (b - 30) * 4 + wave;
  const bool ok = img < NQ;
  f32x4 acc[4][4];
  ZERO_ACC4(acc)
  if (ok)                                       // overlaps the solve
    gram_accum(feat + (size_t)(NSUP + img) * IMG_STRIDE, acc, r, g);

  if (tid == 0)
    for (int i = 0; i < 5; ++i) spin_flag(&sflag[i]);
  __syncthreads();

  // stage G (bf16) into LDS, row stride 68 (bank-spread, 8B aligned writes)
  unsigned short* Gs = (unsigned short*)smem;   // 5*64*68 ushorts = 43520 B
  for (int e = tid; e < 5120; e += 256) {
    const int e4 = e * 4;
    const int nn = e4 >> 12, rem = e4 & 4095, row = rem >> 6, col = rem & 63;
    *(short4v*)&Gs[nn * 4352 + row * 68 + col] = *(const short4v*)&Gneg[e4];
  }
  __syncthreads();

  float myloss = 0.f;
  float nl[5] = {0.f, 0.f, 0.f, 0.f, 0.f};
  if (ok) {
    #pragma unroll
    for (int R = 0; R < 4; ++R)
      #pragma unroll
      for (int C = 0; C < 4; ++C)
        #pragma unroll
        for (int q = 0; q < 4; ++q) {
          const int row = R * 16 + g * 4 + q, col = C * 16 + r;
          const float cv = acc[R][C][q] * (1.f / 64.f);
          const int idx = row * 68 + col;
          #pragma unroll
          for (int nn = 0; nn < 5; ++nn)
            nl[nn] += b2f((short)Gs[nn * 4352 + idx]) * cv;
        }
    #pragma unroll
    for (int nn = 0; nn < 5; ++nn)
      for (int off = 32; off; off >>= 1) nl[nn] += __shfl_down(nl[nn], off);

    if (lane == 0) {
      float mx = nl[0];
      #pragma unroll
      for (int nn = 1; nn < 5; ++nn) mx = fmaxf(mx, nl[nn]);
      float ex[5], se = 0.f;
      #pragma unroll
      for (int nn = 0; nn < 5; ++nn) { ex[nn] = expf(nl[nn] - mx); se += ex[nn]; }
      const float inv = 1.f / se;
      #pragma unroll
      for (int nn = 0; nn < 5; ++nn) out[img * 5 + nn] = ex[nn] * inv;

      const float sc = scale[0];
      float mx2 = nl[0] * sc;
      #pragma unroll
      for (int nn = 1; nn < 5; ++nn) mx2 = fmaxf(mx2, nl[nn] * sc);
      float se2 = 0.f;
      #pragma unroll
      for (int nn = 0; nn < 5; ++nn) se2 += expf(nl[nn] * sc - mx2);
      myloss = mx2 + logf(se2) - nl[label[img]] * sc;   // -log p[label]
    }
  }

  float* wl = (float*)(smem + 43584);
  if (lane == 0) wl[wave] = ok ? myloss : 0.f;
  __syncthreads();
  if (tid == 0) {
    blockloss[b - 30] = wl[0] + wl[1] + wl[2] + wl[3];
    st_flag(&lflag[b - 30], MAGIC);
  }

  if (b == 30 && wave == 0) {                   // final loss gather, block 30
    for (int i = lane; i < 113; i += 64) spin_flag(&lflag[i]);
    float s = 0.f;
    for (int i = lane; i < 113; i += 64) s += blockloss[i];
    for (int off = 32; off; off >>= 1) s += __shfl_down(s, off);
    if (lane == 0) out[2250] = s / 450.f;
  }
}

extern "C" void kernel_launch(void* const* d_in, const int* in_sizes, int n_in,
                              void* d_out, int out_size, void* d_ws, size_t ws_size,
                              hipStream_t stream) {
  const float* feat  = (const float*)d_in[0];
  const int*   label = (const int*)d_in[1];
  const float* scale = (const float*)d_in[2];
  const float* rvec  = (const float*)d_in[3];
  float* out = (float*)d_out;

  char* ws = (char*)d_ws;
  float*          partial   = (float*)ws;                  //      0 .. 491520
  unsigned short* Gneg      = (unsigned short*)(ws + 491520);   // 40960 B
  float*          blockloss = (float*)(ws + 532480);       //   452 B
  unsigned*       flags     = (unsigned*)(ws + 532992);
  unsigned* gflag = flags;         // 30
  unsigned* sflag = flags + 32;    // 5
  unsigned* lflag = flags + 64;    // 113

  k_fused<<<dim3(143), dim3(256), 0, stream>>>(feat, label, scale, rvec, out,
                                               partial, Gneg, blockloss,
                                               gflag, sflag, lflag);
}